// Round 4
// baseline (12589.976 us; speedup 1.0000x reference)
//
#include <hip/hip_runtime.h>
#include <hip/hip_bf16.h>
#include <math.h>

#define B_ 64
#define T_ 256
#define C_ 2048
#define WE_ 256
#define H_ 1024
#define G3_ 3072

typedef __attribute__((ext_vector_type(8))) short short8;
typedef __attribute__((ext_vector_type(4))) float f32x4;

__device__ __forceinline__ float sigmoidf_(float x) { return 1.f / (1.f + expf(-x)); }

__device__ __forceinline__ unsigned short f2bf(float v) {
    union { float f; unsigned int u; } x; x.f = v;
    unsigned int r = x.u + 0x7fffu + ((x.u >> 16) & 1u);
    return (unsigned short)(r >> 16);
}
__device__ __forceinline__ float bf2f(unsigned short h) {
    union { unsigned int u; float f; } x; x.u = ((unsigned int)h) << 16;
    return x.f;
}

#define LD8(p, off) (*(const short8*)((p) + (off)))

// ---------------- prep ----------------

__global__ void k_zero(unsigned int* __restrict__ p) {
    p[blockIdx.x * 256 + threadIdx.x] = 0u;   // grid 128 -> 32768 uints = 131072 B
}

__global__ void k_maskprep(const unsigned char* __restrict__ m, float* __restrict__ mf) {
    int idx = blockIdx.x * 256 + threadIdx.x;  // 0..16383
    bool bytemode = (m[1] != 0);               // mask[0][1] always true (words_num>=128)
    unsigned char v = bytemode ? m[idx] : m[(size_t)idx * 4];
    mf[idx] = v ? 1.f : 0.f;
}

// slot 0 of H ([t][b][k] layout): h0 = enc[:, -1, :]
__global__ void k_hinit0(const float* __restrict__ enc,
                         unsigned short* __restrict__ Hh, unsigned short* __restrict__ Hl) {
    int idx = blockIdx.x * 256 + threadIdx.x;  // 0..65535 = b*1024+k
    int b = idx >> 10, k = idx & 1023;
    float v = enc[((size_t)b * T_ + (T_ - 1)) * H_ + k];
    unsigned short hi = f2bf(v);
    Hh[idx] = hi;
    Hl[idx] = f2bf(v - bf2f(hi));
}

// Wg[j][k] (3072 x 1280): k<256 -> Wih, k>=256 -> Whh; hi/lo bf16.
__global__ void k_wgprep(const float* __restrict__ Wih, const float* __restrict__ Whh,
                         unsigned short* __restrict__ Wgh, unsigned short* __restrict__ Wgl) {
    int row = blockIdx.x;          // 0..3071
    int c4 = threadIdx.x;          // 0..319
    int col = c4 * 4;
    float4 v = (col < 256) ? *(const float4*)&Wih[(size_t)row * 256 + col]
                           : *(const float4*)&Whh[(size_t)row * 1024 + col - 256];
    unsigned short h[4], l[4];
    float vv[4] = {v.x, v.y, v.z, v.w};
#pragma unroll
    for (int i = 0; i < 4; ++i) { h[i] = f2bf(vv[i]); l[i] = f2bf(vv[i] - bf2f(h[i])); }
    size_t o = (size_t)row * 1280 + col;
    *(uint2*)&Wgh[o] = *(const uint2*)h;
    *(uint2*)&Wgl[o] = *(const uint2*)l;
}

// Xe[t][b][e] hi/lo bf16
__global__ void k_xemb(const float* __restrict__ E, const int* __restrict__ targets,
                       unsigned short* __restrict__ Xeh, unsigned short* __restrict__ Xel) {
    int t = blockIdx.x, b = blockIdx.y, l = threadIdx.x;  // l 0..63
    int id = (t == 0) ? 0 : targets[b * T_ + t - 1];
    float4 v = *(const float4*)&E[(size_t)id * 256 + l * 4];
    unsigned short h[4], lo[4];
    float vv[4] = {v.x, v.y, v.z, v.w};
#pragma unroll
    for (int i = 0; i < 4; ++i) { h[i] = f2bf(vv[i]); lo[i] = f2bf(vv[i] - bf2f(h[i])); }
    size_t o = (size_t)t * 16384 + (size_t)b * 256 + l * 4;
    *(uint2*)&Xeh[o] = *(const uint2*)h;
    *(uint2*)&Xel[o] = *(const uint2*)lo;
}

__global__ void k_encprep(const float* __restrict__ enc,
                          unsigned short* __restrict__ ench, unsigned short* __restrict__ encl) {
    size_t i4 = (size_t)blockIdx.x * 256 + threadIdx.x;
    float4 v = *(const float4*)&enc[i4 * 4];
    unsigned short h[4], l[4];
    float vv[4] = {v.x, v.y, v.z, v.w};
#pragma unroll
    for (int i = 0; i < 4; ++i) { h[i] = f2bf(vv[i]); l[i] = f2bf(vv[i] - bf2f(h[i])); }
    *(uint2*)&ench[i4 * 4] = *(const uint2*)h;
    *(uint2*)&encl[i4 * 4] = *(const uint2*)l;
}

__global__ void k_wprep(const float* __restrict__ Wout, unsigned short* __restrict__ Wb) {
    int i4 = blockIdx.x * 256 + threadIdx.x;
    float4 v = *(const float4*)&Wout[(size_t)i4 * 4];
    unsigned short t[4] = {f2bf(v.x), f2bf(v.y), f2bf(v.z), f2bf(v.w)};
    *(uint2*)&Wb[(size_t)i4 * 4] = *(const uint2*)t;
}

// ---------------- persistent recurrence ----------------
// grid 128 = 64 j-triples x 2 K-halves; block 512 = 8 waves (4 m-waves x 2 k-subs).
// Fragments read directly from global (L2-hot); one grid barrier per step.
__global__ __launch_bounds__(512, 2) void k_rnn(
    const unsigned short* __restrict__ Xeh, const unsigned short* __restrict__ Xel,
    const unsigned short* __restrict__ Wgh, const unsigned short* __restrict__ Wgl,
    const float* __restrict__ bih, const float* __restrict__ bhh,
    unsigned short* __restrict__ Hh, unsigned short* __restrict__ Hl,
    float* __restrict__ gpart, unsigned int* __restrict__ flags,
    unsigned int* __restrict__ barcnt)
{
    __shared__ float red[3072];   // 4 m-waves x 3 gates x 64 lanes x f32x4
    const int tid = threadIdx.x;
    const int wave = tid >> 6, lane = tid & 63;
    const int ml = lane & 15, quad = lane >> 4;
    const int mw = wave & 3, ksub = wave >> 2;
    const int triple = blockIdx.x >> 1, kh = blockIdx.x & 1;
    const int j0 = triple * 16;
    const int m0 = mw * 16;
    const int kbase = kh * 640 + ksub * 320;

    float bRv = 0.f, bZv = 0.f, bNXv = 0.f, bNHv = 0.f;
    if (kh == 0 && ksub == 0) {
        int j = j0 + ml;
        bRv = bih[j] + bhh[j];
        bZv = bih[1024 + j] + bhh[1024 + j];
        bNXv = bih[2048 + j];
        bNHv = bhh[2048 + j];
    }

    // B row pointers (constant over t)
    const size_t bo = (size_t)(j0 + ml) * 1280 + quad * 8;
    const unsigned short* BrH = Wgh + bo;
    const unsigned short* BrL = Wgl + bo;
    const unsigned short* BzH = Wgh + bo + (size_t)1024 * 1280;
    const unsigned short* BzL = Wgl + bo + (size_t)1024 * 1280;
    const unsigned short* BnH = Wgh + bo + (size_t)2048 * 1280;
    const unsigned short* BnL = Wgl + bo + (size_t)2048 * 1280;

    // A pointers (advance per step)
    const unsigned short* AxH = Xeh + (size_t)(m0 + ml) * 256 + quad * 8;
    const unsigned short* AxL = Xel + (size_t)(m0 + ml) * 256 + quad * 8;
    // h-region pointer arranged so (ptr + k0) is valid for k0>=256:
    const unsigned short* AhH = Hh + (size_t)(m0 + ml) * 1024 + quad * 8 - 256;
    const unsigned short* AhL = Hl + (size_t)(m0 + ml) * 1024 + quad * 8 - 256;
    const unsigned short* Hh_t = Hh;   // slot t base
    const unsigned short* Hl_t = Hl;

    for (int t = 0; t < 256; ++t) {
        f32x4 aR = {0,0,0,0}, aZ = {0,0,0,0}, aNX = {0,0,0,0}, aNH = {0,0,0,0};
        // prefetch chunk 0
        short8 cah, cal, cb0h, cb0l, cb1h, cb1l, cb2h, cb2l;
        {
            int k0 = kbase;
            if (k0 < 256) { cah = LD8(AxH, k0); cal = LD8(AxL, k0); }
            else          { cah = LD8(AhH, k0); cal = LD8(AhL, k0); }
            cb0h = LD8(BrH, k0); cb0l = LD8(BrL, k0);
            cb1h = LD8(BzH, k0); cb1l = LD8(BzL, k0);
            cb2h = LD8(BnH, k0); cb2l = LD8(BnL, k0);
        }
#pragma unroll
        for (int c = 0; c < 10; ++c) {
            short8 nah, nal, nb0h, nb0l, nb1h, nb1l, nb2h, nb2l;
            if (c < 9) {
                int k0n = kbase + (c + 1) * 32;
                if (k0n < 256) { nah = LD8(AxH, k0n); nal = LD8(AxL, k0n); }
                else           { nah = LD8(AhH, k0n); nal = LD8(AhL, k0n); }
                nb0h = LD8(BrH, k0n); nb0l = LD8(BrL, k0n);
                nb1h = LD8(BzH, k0n); nb1l = LD8(BzL, k0n);
                nb2h = LD8(BnH, k0n); nb2l = LD8(BnL, k0n);
            }
            aR = __builtin_amdgcn_mfma_f32_16x16x32_bf16(cah, cb0h, aR, 0, 0, 0);
            aR = __builtin_amdgcn_mfma_f32_16x16x32_bf16(cah, cb0l, aR, 0, 0, 0);
            aR = __builtin_amdgcn_mfma_f32_16x16x32_bf16(cal, cb0h, aR, 0, 0, 0);
            aZ = __builtin_amdgcn_mfma_f32_16x16x32_bf16(cah, cb1h, aZ, 0, 0, 0);
            aZ = __builtin_amdgcn_mfma_f32_16x16x32_bf16(cah, cb1l, aZ, 0, 0, 0);
            aZ = __builtin_amdgcn_mfma_f32_16x16x32_bf16(cal, cb1h, aZ, 0, 0, 0);
            if (kbase + c * 32 < 256) {
                aNX = __builtin_amdgcn_mfma_f32_16x16x32_bf16(cah, cb2h, aNX, 0, 0, 0);
                aNX = __builtin_amdgcn_mfma_f32_16x16x32_bf16(cah, cb2l, aNX, 0, 0, 0);
                aNX = __builtin_amdgcn_mfma_f32_16x16x32_bf16(cal, cb2h, aNX, 0, 0, 0);
            } else {
                aNH = __builtin_amdgcn_mfma_f32_16x16x32_bf16(cah, cb2h, aNH, 0, 0, 0);
                aNH = __builtin_amdgcn_mfma_f32_16x16x32_bf16(cah, cb2l, aNH, 0, 0, 0);
                aNH = __builtin_amdgcn_mfma_f32_16x16x32_bf16(cal, cb2h, aNH, 0, 0, 0);
            }
            if (c < 9) {
                cah = nah; cal = nal;
                cb0h = nb0h; cb0l = nb0l;
                cb1h = nb1h; cb1l = nb1l;
                cb2h = nb2h; cb2l = nb2l;
            }
        }
        // intra-block reduce over ksub
        if (ksub == 1) {
            *(f32x4*)&red[((mw * 3 + 0) * 64 + lane) * 4] = aR;
            *(f32x4*)&red[((mw * 3 + 1) * 64 + lane) * 4] = aZ;
            *(f32x4*)&red[((mw * 3 + 2) * 64 + lane) * 4] = aNH;
        }
        __syncthreads();
        if (ksub == 0) {
            aR  += *(const f32x4*)&red[((mw * 3 + 0) * 64 + lane) * 4];
            aZ  += *(const f32x4*)&red[((mw * 3 + 1) * 64 + lane) * 4];
            aNH += *(const f32x4*)&red[((mw * 3 + 2) * 64 + lane) * 4];
        }
        // cross-block: kh1 publishes partials, kh0 consumes + epilogue
        if (kh == 1) {
            if (ksub == 0) {
#pragma unroll
                for (int reg = 0; reg < 4; ++reg) {
                    int b = m0 + quad * 4 + reg;
                    gpart[((triple * 3 + 0) * 64 + b) * 16 + ml] = aR[reg];
                    gpart[((triple * 3 + 1) * 64 + b) * 16 + ml] = aZ[reg];
                    gpart[((triple * 3 + 2) * 64 + b) * 16 + ml] = aNH[reg];
                }
                __threadfence();
            }
            __syncthreads();
            if (tid == 0)
                __hip_atomic_store(&flags[t * 64 + triple], 1u,
                                   __ATOMIC_RELEASE, __HIP_MEMORY_SCOPE_AGENT);
        } else {
            if (tid == 0) {
                while (__hip_atomic_load(&flags[t * 64 + triple],
                                         __ATOMIC_ACQUIRE, __HIP_MEMORY_SCOPE_AGENT) == 0u)
                    __builtin_amdgcn_s_sleep(1);
            }
            __syncthreads();
            if (ksub == 0) {
                int j = j0 + ml;
                size_t slotN = (size_t)(t + 1) * 65536;
#pragma unroll
                for (int reg = 0; reg < 4; ++reg) {
                    int b = m0 + quad * 4 + reg;
                    float R  = aR[reg]  + gpart[((triple * 3 + 0) * 64 + b) * 16 + ml] + bRv;
                    float Z  = aZ[reg]  + gpart[((triple * 3 + 1) * 64 + b) * 16 + ml] + bZv;
                    float NH = aNH[reg] + gpart[((triple * 3 + 2) * 64 + b) * 16 + ml] + bNHv;
                    float rr = sigmoidf_(R), zz = sigmoidf_(Z);
                    float nn = tanhf(aNX[reg] + bNXv + rr * NH);
                    size_t po = (size_t)b * 1024 + j;
                    float hp = bf2f(Hh_t[po]) + bf2f(Hl_t[po]);
                    float hv = (1.f - zz) * nn + zz * hp;
                    unsigned short hi = f2bf(hv);
                    Hh[slotN + po] = hi;
                    Hl[slotN + po] = f2bf(hv - bf2f(hi));
                }
                __threadfence();
            }
        }
        // grid barrier
        __syncthreads();
        if (tid == 0) {
            __hip_atomic_fetch_add(barcnt, 1u, __ATOMIC_RELEASE, __HIP_MEMORY_SCOPE_AGENT);
            unsigned int target = 128u * (unsigned int)(t + 1);
            while (__hip_atomic_load(barcnt, __ATOMIC_ACQUIRE, __HIP_MEMORY_SCOPE_AGENT) < target)
                __builtin_amdgcn_s_sleep(2);
        }
        __syncthreads();
        // advance per-step pointers
        AxH += 16384; AxL += 16384;
        AhH += 65536; AhL += 65536;
        Hh_t += 65536; Hl_t += 65536;
    }
}

// ---------------- batched attention + logits ----------------

// e[b][t][t'] = h_t[b] . enc[b][t'], bf16x2 MFMA. grid (4, 64).
__global__ __launch_bounds__(256) void k_scoresK(
    const unsigned short* __restrict__ Hh, const unsigned short* __restrict__ Hl,
    const unsigned short* __restrict__ ench, const unsigned short* __restrict__ encl,
    float* __restrict__ e_all)
{
    __shared__ unsigned short Ahs[128 * 40], Als[128 * 40], Bhs[128 * 40], Bls[128 * 40];
    const int tid = threadIdx.x;
    const int b = blockIdx.y;
    const int t0 = (blockIdx.x & 1) * 128, p0 = (blockIdx.x >> 1) * 128;
    const int lane = tid & 63, wave = tid >> 6;
    const int wm = (wave & 1) * 64, wn = (wave >> 1) * 64;
    const int ml = lane & 15, quad = lane >> 4;
    f32x4 acc[4][4];
#pragma unroll
    for (int a = 0; a < 4; ++a)
#pragma unroll
        for (int c = 0; c < 4; ++c) acc[a][c] = (f32x4){0.f, 0.f, 0.f, 0.f};

    for (int kc = 0; kc < 32; ++kc) {
#pragma unroll
        for (int r2 = 0; r2 < 2; ++r2) {
            int s = tid + 256 * r2;
            int row = s >> 2, q = s & 3;
            size_t ga = ((size_t)(t0 + row + 1) * 64 + b) * 1024 + kc * 32 + q * 8;
            size_t gb = ((size_t)b * 256 + p0 + row) * 1024 + kc * 32 + q * 8;
            *(uint4*)&Ahs[row * 40 + q * 8] = *(const uint4*)&Hh[ga];
            *(uint4*)&Als[row * 40 + q * 8] = *(const uint4*)&Hl[ga];
            *(uint4*)&Bhs[row * 40 + q * 8] = *(const uint4*)&ench[gb];
            *(uint4*)&Bls[row * 40 + q * 8] = *(const uint4*)&encl[gb];
        }
        __syncthreads();
        short8 ah[4], al[4], bh[4], bl[4];
#pragma unroll
        for (int mt = 0; mt < 4; ++mt) {
            ah[mt] = *(const short8*)&Ahs[(wm + mt * 16 + ml) * 40 + quad * 8];
            al[mt] = *(const short8*)&Als[(wm + mt * 16 + ml) * 40 + quad * 8];
        }
#pragma unroll
        for (int nt = 0; nt < 4; ++nt) {
            bh[nt] = *(const short8*)&Bhs[(wn + nt * 16 + ml) * 40 + quad * 8];
            bl[nt] = *(const short8*)&Bls[(wn + nt * 16 + ml) * 40 + quad * 8];
        }
#pragma unroll
        for (int mt = 0; mt < 4; ++mt)
#pragma unroll
            for (int nt = 0; nt < 4; ++nt) {
                acc[mt][nt] = __builtin_amdgcn_mfma_f32_16x16x32_bf16(ah[mt], bh[nt], acc[mt][nt], 0, 0, 0);
                acc[mt][nt] = __builtin_amdgcn_mfma_f32_16x16x32_bf16(ah[mt], bl[nt], acc[mt][nt], 0, 0, 0);
                acc[mt][nt] = __builtin_amdgcn_mfma_f32_16x16x32_bf16(al[mt], bh[nt], acc[mt][nt], 0, 0, 0);
            }
        __syncthreads();
    }
#pragma unroll
    for (int mt = 0; mt < 4; ++mt)
#pragma unroll
        for (int nt = 0; nt < 4; ++nt)
#pragma unroll
            for (int reg = 0; reg < 4; ++reg) {
                int t = t0 + wm + mt * 16 + quad * 4 + reg;
                int p = p0 + wn + nt * 16 + ml;
                e_all[((size_t)b * 256 + t) * 256 + p] = acc[mt][nt][reg];
            }
}

__global__ __launch_bounds__(256) void k_softmaxK(
    const float* __restrict__ e_all, const float* __restrict__ maskf,
    unsigned short* __restrict__ Ab)
{
    const int tid = threadIdx.x;
    const int ridx = blockIdx.x * 4 + (tid >> 6);
    const int lane = tid & 63;
    const int b = ridx >> 8, t = ridx & 255;
    const float* er = e_all + ((size_t)b * 256 + t) * 256;
    const float* mr = maskf + (size_t)b * 256;
    float v[4];
#pragma unroll
    for (int i = 0; i < 4; ++i) {
        int p = lane + 64 * i;
        v[i] = (mr[p] > 0.5f) ? er[p] : -INFINITY;
    }
    float m = fmaxf(fmaxf(v[0], v[1]), fmaxf(v[2], v[3]));
#pragma unroll
    for (int off = 32; off > 0; off >>= 1) m = fmaxf(m, __shfl_xor(m, off));
    float s = 0.f;
#pragma unroll
    for (int i = 0; i < 4; ++i) { v[i] = expf(v[i] - m); s += v[i]; }
#pragma unroll
    for (int off = 32; off > 0; off >>= 1) s += __shfl_xor(s, off);
    float inv = 1.f / s;
    unsigned short* arr = Ab + ((size_t)b * 256 + t) * 256;
#pragma unroll
    for (int i = 0; i < 4; ++i) arr[lane + 64 * i] = f2bf(v[i] * inv);
}

// C[b][t][k] = sum_t' alpha[b][t][t'] * enc[b][t'][k]. grid (16, 64).
__global__ __launch_bounds__(256) void k_contextK(
    const unsigned short* __restrict__ Ab, const unsigned short* __restrict__ ench,
    unsigned short* __restrict__ Cb)
{
    __shared__ unsigned short As[128 * 40];
    __shared__ unsigned short Bs[128 * 40];   // [k][t'] transposed
    const int tid = threadIdx.x;
    const int b = blockIdx.y;
    const int t0 = (blockIdx.x & 1) * 128;
    const int k0 = (blockIdx.x >> 1) * 128;
    const int lane = tid & 63, wave = tid >> 6;
    const int wm = (wave & 1) * 64, wn = (wave >> 1) * 64;
    const int ml = lane & 15, quad = lane >> 4;
    f32x4 acc[4][4];
#pragma unroll
    for (int a = 0; a < 4; ++a)
#pragma unroll
        for (int c = 0; c < 4; ++c) acc[a][c] = (f32x4){0.f, 0.f, 0.f, 0.f};

    for (int c = 0; c < 8; ++c) {
#pragma unroll
        for (int r2 = 0; r2 < 2; ++r2) {
            int s = tid + 256 * r2;
            int row = s >> 2, q = s & 3;
            *(uint4*)&As[row * 40 + q * 8] =
                *(const uint4*)&Ab[((size_t)b * 256 + t0 + row) * 256 + c * 32 + q * 8];
        }
        {
            int tr = tid >> 3, kq = tid & 7;
            const unsigned short* src =
                ench + ((size_t)b * 256 + c * 32 + tr) * 1024 + k0 + kq * 16;
            unsigned short tmp[16];
            *(uint4*)&tmp[0] = *(const uint4*)&src[0];
            *(uint4*)&tmp[8] = *(const uint4*)&src[8];
#pragma unroll
            for (int i = 0; i < 16; ++i)
                Bs[(kq * 16 + i) * 40 + tr] = tmp[i];
        }
        __syncthreads();
        short8 af[4], bf[4];
#pragma unroll
        for (int mt = 0; mt < 4; ++mt)
            af[mt] = *(const short8*)&As[(wm + mt * 16 + ml) * 40 + quad * 8];
#pragma unroll
        for (int nt = 0; nt < 4; ++nt)
            bf[nt] = *(const short8*)&Bs[(wn + nt * 16 + ml) * 40 + quad * 8];
#pragma unroll
        for (int mt = 0; mt < 4; ++mt)
#pragma unroll
            for (int nt = 0; nt < 4; ++nt)
                acc[mt][nt] = __builtin_amdgcn_mfma_f32_16x16x32_bf16(af[mt], bf[nt], acc[mt][nt], 0, 0, 0);
        __syncthreads();
    }
#pragma unroll
    for (int mt = 0; mt < 4; ++mt)
#pragma unroll
        for (int nt = 0; nt < 4; ++nt)
#pragma unroll
            for (int reg = 0; reg < 4; ++reg) {
                int t = t0 + wm + mt * 16 + quad * 4 + reg;
                int k = k0 + wn + nt * 16 + ml;
                Cb[((size_t)b * 256 + t) * 1024 + k] = f2bf(acc[mt][nt][reg]);
            }
}

// out[r][j] = [H|C][r] . Wb[j] + bout[j]; M=16384, N=2048, K=2048. r = b*256+t.
__global__ __launch_bounds__(256) void k_finalK(
    const unsigned short* __restrict__ Hh, const unsigned short* __restrict__ Cb,
    const unsigned short* __restrict__ Wb,
    const float* __restrict__ bout, float* __restrict__ out)
{
    __shared__ unsigned short As[128 * 40];
    __shared__ unsigned short Bs[128 * 40];
    const int tid = threadIdx.x;
    const int gr0 = blockIdx.x * 128;
    const int j0  = blockIdx.y * 128;
    const int lane = tid & 63, wave = tid >> 6;
    const int wm = (wave & 1) * 64, wn = (wave >> 1) * 64;
    const int ml = lane & 15, quad = lane >> 4;
    f32x4 acc[4][4];
#pragma unroll
    for (int a = 0; a < 4; ++a)
#pragma unroll
        for (int c = 0; c < 4; ++c) acc[a][c] = (f32x4){0.f, 0.f, 0.f, 0.f};

    for (int kc = 0; kc < 64; ++kc) {
        int ko = (kc & 31) * 32;
#pragma unroll
        for (int r2 = 0; r2 < 2; ++r2) {
            int s = tid + 256 * r2;
            int row = s >> 2, q = s & 3;
            int r0 = gr0 + row;
            size_t ga;
            if (kc < 32) ga = ((size_t)((r0 & 255) + 1) * 64 + (r0 >> 8)) * 1024 + ko + q * 8;
            else         ga = (size_t)r0 * 1024 + ko + q * 8;
            const unsigned short* asrc = (kc < 32) ? Hh : Cb;
            *(uint4*)&As[row * 40 + q * 8] = *(const uint4*)&asrc[ga];
            *(uint4*)&Bs[row * 40 + q * 8] =
                *(const uint4*)&Wb[(size_t)(j0 + row) * 2048 + kc * 32 + q * 8];
        }
        __syncthreads();
        short8 af[4], bf[4];
#pragma unroll
        for (int mt = 0; mt < 4; ++mt)
            af[mt] = *(const short8*)&As[(wm + mt * 16 + ml) * 40 + quad * 8];
#pragma unroll
        for (int nt = 0; nt < 4; ++nt)
            bf[nt] = *(const short8*)&Bs[(wn + nt * 16 + ml) * 40 + quad * 8];
#pragma unroll
        for (int mt = 0; mt < 4; ++mt)
#pragma unroll
            for (int nt = 0; nt < 4; ++nt)
                acc[mt][nt] = __builtin_amdgcn_mfma_f32_16x16x32_bf16(af[mt], bf[nt], acc[mt][nt], 0, 0, 0);
        __syncthreads();
    }
#pragma unroll
    for (int nt = 0; nt < 4; ++nt) {
        int j = j0 + wn + nt * 16 + ml;
        float bo = bout[j];
#pragma unroll
        for (int mt = 0; mt < 4; ++mt)
#pragma unroll
            for (int reg = 0; reg < 4; ++reg) {
                int r = gr0 + wm + mt * 16 + quad * 4 + reg;
                out[(size_t)r * 2048 + j] = acc[mt][nt][reg] + bo;
            }
    }
}

// ---------------- FALLBACK (round-2) path ----------------

__global__ void k_hinit(const float* __restrict__ enc, float* __restrict__ h) {
    int idx = blockIdx.x * 256 + threadIdx.x;
    int b = idx >> 10, k = idx & (H_ - 1);
    h[idx] = enc[((size_t)b * T_ + (T_ - 1)) * H_ + k];
}

__global__ __launch_bounds__(256) void k_gates(
    const float* __restrict__ E, const int* __restrict__ targets,
    const float* __restrict__ Wih, const float* __restrict__ Whh,
    const float* __restrict__ bih, const float* __restrict__ bhh,
    const float* __restrict__ h_cur,
    float* __restrict__ gi, float* __restrict__ gh0, float* __restrict__ gh1,
    int t)
{
    __shared__ float As[32 * 68];
    __shared__ float Ws[32 * 34];
    __shared__ int ids[B_];
    const int tid = threadIdx.x;
    const int z = blockIdx.y;
    const int j0 = blockIdx.x * 32;
    const int tx = tid & 15;
    const int ty = tid >> 4;
    float accI[4][2], accH[4][2];
#pragma unroll
    for (int i = 0; i < 4; ++i) { accI[i][0]=0.f; accI[i][1]=0.f; accH[i][0]=0.f; accH[i][1]=0.f; }
    if (tid < B_) ids[tid] = (t == 0) ? 0 : targets[tid * T_ + t - 1];
    __syncthreads();
    if (z == 0) {
        for (int c = 0; c < 8; ++c) {
            int k0 = c * 32;
#pragma unroll
            for (int r = 0; r < 2; ++r) {
                int lin = tid + 256 * r;
                int k4 = lin & 7, b = lin >> 3;
                float4 v = *(const float4*)&E[(size_t)ids[b] * WE_ + k0 + k4 * 4];
                int kk = k4 * 4;
                As[(kk + 0) * 68 + b] = v.x; As[(kk + 1) * 68 + b] = v.y;
                As[(kk + 2) * 68 + b] = v.z; As[(kk + 3) * 68 + b] = v.w;
            }
            {
                int k4 = tid & 7, jj = tid >> 3;
                float4 v = *(const float4*)&Wih[(size_t)(j0 + jj) * WE_ + k0 + k4 * 4];
                int kk = k4 * 4;
                Ws[(kk + 0) * 34 + jj] = v.x; Ws[(kk + 1) * 34 + jj] = v.y;
                Ws[(kk + 2) * 34 + jj] = v.z; Ws[(kk + 3) * 34 + jj] = v.w;
            }
            __syncthreads();
#pragma unroll
            for (int kk = 0; kk < 32; ++kk) {
                float4 a = *(const float4*)&As[kk * 68 + ty * 4];
                float2 w = *(const float2*)&Ws[kk * 34 + tx * 2];
                accI[0][0] += a.x * w.x; accI[0][1] += a.x * w.y;
                accI[1][0] += a.y * w.x; accI[1][1] += a.y * w.y;
                accI[2][0] += a.z * w.x; accI[2][1] += a.z * w.y;
                accI[3][0] += a.w * w.x; accI[3][1] += a.w * w.y;
            }
            __syncthreads();
        }
    }
    const int c_lo = (z == 0) ? 0 : 12;
    const int c_hi = (z == 0) ? 12 : 32;
    for (int c = c_lo; c < c_hi; ++c) {
        int k0 = c * 32;
#pragma unroll
        for (int r = 0; r < 2; ++r) {
            int lin = tid + 256 * r;
            int k4 = lin & 7, b = lin >> 3;
            float4 v = *(const float4*)&h_cur[(size_t)b * H_ + k0 + k4 * 4];
            int kk = k4 * 4;
            As[(kk + 0) * 68 + b] = v.x; As[(kk + 1) * 68 + b] = v.y;
            As[(kk + 2) * 68 + b] = v.z; As[(kk + 3) * 68 + b] = v.w;
        }
        {
            int k4 = tid & 7, jj = tid >> 3;
            float4 v = *(const float4*)&Whh[(size_t)(j0 + jj) * H_ + k0 + k4 * 4];
            int kk = k4 * 4;
            Ws[(kk + 0) * 34 + jj] = v.x; Ws[(kk + 1) * 34 + jj] = v.y;
            Ws[(kk + 2) * 34 + jj] = v.z; Ws[(kk + 3) * 34 + jj] = v.w;
        }
        __syncthreads();
#pragma unroll
        for (int kk = 0; kk < 32; ++kk) {
            float4 a = *(const float4*)&As[kk * 68 + ty * 4];
            float2 w = *(const float2*)&Ws[kk * 34 + tx * 2];
            accH[0][0] += a.x * w.x; accH[0][1] += a.x * w.y;
            accH[1][0] += a.y * w.x; accH[1][1] += a.y * w.y;
            accH[2][0] += a.z * w.x; accH[2][1] += a.z * w.y;
            accH[3][0] += a.w * w.x; accH[3][1] += a.w * w.y;
        }
        __syncthreads();
    }
#pragma unroll
    for (int p = 0; p < 2; ++p) {
        int j = j0 + tx * 2 + p;
        if (z == 0) {
            float vi = bih[j], vh = bhh[j];
#pragma unroll
            for (int i = 0; i < 4; ++i) {
                int b = ty * 4 + i;
                gi[(size_t)b * G3_ + j]  = accI[i][p] + vi;
                gh0[(size_t)b * G3_ + j] = accH[i][p] + vh;
            }
        } else {
#pragma unroll
            for (int i = 0; i < 4; ++i) {
                int b = ty * 4 + i;
                gh1[(size_t)b * G3_ + j] = accH[i][p];
            }
        }
    }
}

__global__ __launch_bounds__(256) void k_score_h(
    const float* __restrict__ gi, const float* __restrict__ gh0, const float* __restrict__ gh1,
    const float* __restrict__ h_prev, const float* __restrict__ enc,
    float* __restrict__ e_raw, float* __restrict__ h_next,
    __hip_bfloat16* __restrict__ Xb, int t, int use_x)
{
    __shared__ float hs[H_];
    const int b = blockIdx.y;
    const int tc = blockIdx.x;
    const int tid = threadIdx.x;
#pragma unroll
    for (int i = 0; i < 4; ++i) {
        int k = i * 256 + tid;
        size_t o = (size_t)b * G3_ + k;
        float ir = gi[o], iz = gi[o + H_], in = gi[o + 2 * H_];
        float hr = gh0[o] + gh1[o];
        float hz = gh0[o + H_] + gh1[o + H_];
        float hn = gh0[o + 2 * H_] + gh1[o + 2 * H_];
        float r = sigmoidf_(ir + hr);
        float z = sigmoidf_(iz + hz);
        float n = tanhf(in + r * hn);
        float hv = (1.f - z) * n + z * h_prev[(size_t)b * H_ + k];
        hs[k] = hv;
        if (tc == 0) {
            h_next[(size_t)b * H_ + k] = hv;
            if (use_x) Xb[((size_t)b * T_ + t) * C_ + k] = __float2bfloat16(hv);
        }
    }
    __syncthreads();
    const int tl = tid >> 2, part = tid & 3;
    const int tt = tc * 64 + tl;
    const float4* row = (const float4*)(enc + ((size_t)b * T_ + tt) * H_);
    const float4* hv4 = (const float4*)hs;
    float acc = 0.f;
#pragma unroll 8
    for (int i = 0; i < 64; ++i) {
        float4 a = row[part * 64 + i];
        float4 x = hv4[part * 64 + i];
        acc += a.x * x.x + a.y * x.y + a.z * x.z + a.w * x.w;
    }
    acc += __shfl_xor(acc, 1);
    acc += __shfl_xor(acc, 2);
    if (part == 0) e_raw[(size_t)b * T_ + tt] = acc;
}

__global__ __launch_bounds__(256) void k_ctx(
    const float* __restrict__ e_raw, const float* __restrict__ maskf,
    const float* __restrict__ enc, float* __restrict__ cvec,
    __hip_bfloat16* __restrict__ Xb, int t, int use_x)
{
    __shared__ float al[T_];
    __shared__ float red[256];
    const int b = blockIdx.y, q = blockIdx.x, tid = threadIdx.x;
    float e = (maskf[(size_t)b * T_ + tid] > 0.5f) ? e_raw[(size_t)b * T_ + tid] : -INFINITY;
    red[tid] = e; __syncthreads();
    for (int s = 128; s > 0; s >>= 1) { if (tid < s) red[tid] = fmaxf(red[tid], red[tid + s]); __syncthreads(); }
    float mx = red[0]; __syncthreads();
    float p = expf(e - mx);
    red[tid] = p; __syncthreads();
    for (int s = 128; s > 0; s >>= 1) { if (tid < s) red[tid] += red[tid + s]; __syncthreads(); }
    float denom = red[0];
    al[tid] = p / denom;
    __syncthreads();
    const int k = q * 256 + tid;
    float acc = 0.f;
#pragma unroll 8
    for (int tt2 = 0; tt2 < T_; ++tt2) {
        acc += al[tt2] * enc[((size_t)b * T_ + tt2) * H_ + k];
    }
    if (use_x) Xb[((size_t)b * T_ + t) * C_ + H_ + k] = __float2bfloat16(acc);
    else       cvec[(size_t)b * H_ + k] = acc;
}

__global__ __launch_bounds__(256) void k_logits(
    const float* __restrict__ h, const float* __restrict__ cvec,
    const float* __restrict__ Wout, const float* __restrict__ bout,
    float* __restrict__ out, int t)
{
    __shared__ float As[32 * 68];
    __shared__ float Ws[32 * 33];
    const int tid = threadIdx.x;
    const int j0 = blockIdx.x * 32;
    const int tx = tid & 31;
    const int ty = tid >> 5;
    float acc[8];
#pragma unroll
    for (int i = 0; i < 8; ++i) acc[i] = 0.f;
    for (int c = 0; c < 64; ++c) {
        int k0 = c * 32;
        const float* Ap = (k0 < H_) ? (h + k0) : (cvec + (k0 - H_));
#pragma unroll
        for (int r = 0; r < 2; ++r) {
            int lin = tid + 256 * r;
            int k4 = lin & 7, b = lin >> 3;
            float4 v = *(const float4*)&Ap[(size_t)b * H_ + k4 * 4];
            int kk = k4 * 4;
            As[(kk + 0) * 68 + b] = v.x; As[(kk + 1) * 68 + b] = v.y;
            As[(kk + 2) * 68 + b] = v.z; As[(kk + 3) * 68 + b] = v.w;
        }
        {
            int k4 = tid & 7, jj = tid >> 3;
            float4 v = *(const float4*)&Wout[(size_t)(j0 + jj) * (2 * H_) + k0 + k4 * 4];
            int kk = k4 * 4;
            Ws[(kk + 0) * 33 + jj] = v.x; Ws[(kk + 1) * 33 + jj] = v.y;
            Ws[(kk + 2) * 33 + jj] = v.z; Ws[(kk + 3) * 33 + jj] = v.w;
        }
        __syncthreads();
#pragma unroll
        for (int kk = 0; kk < 32; ++kk) {
            float w = Ws[kk * 33 + tx];
#pragma unroll
            for (int i = 0; i < 8; ++i) acc[i] += As[kk * 68 + ty * 8 + i] * w;
        }
        __syncthreads();
    }
    float bo = bout[j0 + tx];
#pragma unroll
    for (int i = 0; i < 8; ++i) {
        int b = ty * 8 + i;
        out[((size_t)b * T_ + t) * C_ + j0 + tx] = acc[i] + bo;
    }
}

__global__ __launch_bounds__(256) void k_final(
    const __hip_bfloat16* __restrict__ Xb, const __hip_bfloat16* __restrict__ Wb,
    const float* __restrict__ bout, float* __restrict__ out)
{
    __shared__ __hip_bfloat16 As[128 * 40];
    __shared__ __hip_bfloat16 Bs[128 * 40];
    const int tid = threadIdx.x;
    const int gr0 = blockIdx.x * 128;
    const int j0  = blockIdx.y * 128;
    const int lane = tid & 63, wave = tid >> 6;
    const int wm = (wave & 1) * 64, wn = (wave >> 1) * 64;
    const int ml = lane & 15, quad = lane >> 4;
    f32x4 acc[4][4];
#pragma unroll
    for (int a = 0; a < 4; ++a)
#pragma unroll
        for (int b = 0; b < 4; ++b) acc[a][b] = (f32x4){0.f, 0.f, 0.f, 0.f};
    for (int kc = 0; kc < 64; ++kc) {
#pragma unroll
        for (int r = 0; r < 2; ++r) {
            int s = tid + 256 * r;
            int row = s >> 2, kq = s & 3;
            *(uint4*)&As[row * 40 + kq * 8] =
                *(const uint4*)&Xb[(size_t)(gr0 + row) * 2048 + kc * 32 + kq * 8];
            *(uint4*)&Bs[row * 40 + kq * 8] =
                *(const uint4*)&Wb[(size_t)(j0 + row) * 2048 + kc * 32 + kq * 8];
        }
        __syncthreads();
        short8 af[4], bf[4];
#pragma unroll
        for (int mt = 0; mt < 4; ++mt)
            af[mt] = *(const short8*)&As[(wm + mt * 16 + ml) * 40 + quad * 8];
#pragma unroll
        for (int nt = 0; nt < 4; ++nt)
            bf[nt] = *(const short8*)&Bs[(wn + nt * 16 + ml) * 40 + quad * 8];
#pragma unroll
        for (int mt = 0; mt < 4; ++mt)
#pragma unroll
            for (int nt = 0; nt < 4; ++nt)
                acc[mt][nt] = __builtin_amdgcn_mfma_f32_16x16x32_bf16(af[mt], bf[nt], acc[mt][nt], 0, 0, 0);
        __syncthreads();
    }
#pragma unroll
    for (int nt = 0; nt < 4; ++nt) {
        int j = j0 + wn + nt * 16 + ml;
        float bo = bout[j];
#pragma unroll
        for (int mt = 0; mt < 4; ++mt) {
#pragma unroll
            for (int reg = 0; reg < 4; ++reg) {
                int r = gr0 + wm + mt * 16 + quad * 4 + reg;
                out[(size_t)r * 2048 + j] = acc[mt][nt][reg] + bo;
            }
        }
    }
}

// ---------------- host ----------------

extern "C" void kernel_launch(void* const* d_in, const int* in_sizes, int n_in,
                              void* d_out, int out_size, void* d_ws, size_t ws_size,
                              hipStream_t stream)
{
    const float* enc     = (const float*)d_in[0];
    const unsigned char* mask = (const unsigned char*)d_in[1];
    const int*   targets = (const int*)d_in[2];
    const float* E       = (const float*)d_in[3];
    const float* Wih     = (const float*)d_in[4];
    const float* Whh     = (const float*)d_in[5];
    const float* bih     = (const float*)d_in[6];
    const float* bhh     = (const float*)d_in[7];
    const float* Wout    = (const float*)d_in[8];
    const float* bout    = (const float*)d_in[9];
    float* out = (float*)d_out;

    const size_t NEED_FULL = 218300416ull;  // layout below
    const size_t NEED_MID  = 819200ull * 4 + (4194304ull + 33554432ull) * 2;  // ~78.8 MB

    if (ws_size >= NEED_FULL) {
        char* p = (char*)d_ws;
        unsigned int* flags = (unsigned int*)p;           // 65536 B flags + counter
        unsigned int* barcnt = flags + 16384;
        p += 131072;
        float* maskf = (float*)p;                p += 65536;
        unsigned short* Wgh = (unsigned short*)p; p += 7864320;
        unsigned short* Wgl = (unsigned short*)p; p += 7864320;
        unsigned short* Xeh = (unsigned short*)p; p += 8388608;
        unsigned short* Xel = (unsigned short*)p; p += 8388608;
        float* e_all = (float*)Xeh;               // alias: Xe dead after k_rnn
        unsigned short* ench = (unsigned short*)p; p += 33554432;
        unsigned short* encl = (unsigned short*)p; p += 33554432;
        unsigned short* Hh = (unsigned short*)p;  p += 33685504;   // 257 slots [t][b][k]
        unsigned short* Hl = (unsigned short*)p;  p += 33685504;
        unsigned short* Ab = (unsigned short*)p;  p += 8388608;
        unsigned short* Cb = (unsigned short*)p;  p += 33554432;
        unsigned short* Wb = (unsigned short*)p;  p += 8388608;
        float* gpart = (float*)p;                 p += 786432;

        k_zero<<<128, 256, 0, stream>>>(flags);
        k_maskprep<<<64, 256, 0, stream>>>(mask, maskf);
        k_hinit0<<<256, 256, 0, stream>>>(enc, Hh, Hl);
        k_wgprep<<<3072, 320, 0, stream>>>(Wih, Whh, Wgh, Wgl);
        k_xemb<<<dim3(256, 64), 64, 0, stream>>>(E, targets, Xeh, Xel);
        k_encprep<<<16384, 256, 0, stream>>>(enc, ench, encl);
        k_wprep<<<4096, 256, 0, stream>>>(Wout, Wb);

        k_rnn<<<128, 512, 0, stream>>>(Xeh, Xel, Wgh, Wgl, bih, bhh,
                                       Hh, Hl, gpart, flags, barcnt);

        k_scoresK<<<dim3(4, 64), 256, 0, stream>>>(Hh, Hl, ench, encl, e_all);
        k_softmaxK<<<4096, 256, 0, stream>>>(e_all, maskf, Ab);
        k_contextK<<<dim3(16, 64), 256, 0, stream>>>(Ab, ench, Cb);
        k_finalK<<<dim3(128, 16), 256, 0, stream>>>(Hh, Cb, Wb, bout, out);
        return;
    }

    // ---- fallback: round-2 structure ----
    float* ws    = (float*)d_ws;
    float* hbuf  = ws;
    float* gi    = ws + 131072;
    float* gh0   = gi + 196608;
    float* gh1   = gh0 + 196608;
    float* e_raw = gh1 + 196608;
    float* maskf = e_raw + 16384;
    float* cvec  = maskf + 16384;
    __hip_bfloat16* Wb = (__hip_bfloat16*)(ws + 819200);
    __hip_bfloat16* Xb = Wb + 4194304;

    const int fast = (ws_size >= NEED_MID) ? 1 : 0;

    k_maskprep<<<64, 256, 0, stream>>>(mask, maskf);
    k_hinit<<<256, 256, 0, stream>>>(enc, hbuf);
    if (fast) k_wprep<<<4096, 256, 0, stream>>>(Wout, (unsigned short*)Wb);

    for (int t = 0; t < T_; ++t) {
        float* h_cur  = hbuf + (t & 1) * 65536;
        float* h_next = hbuf + ((t + 1) & 1) * 65536;
        k_gates<<<dim3(96, 2), 256, 0, stream>>>(E, targets, Wih, Whh, bih, bhh,
                                                 h_cur, gi, gh0, gh1, t);
        k_score_h<<<dim3(4, 64), 256, 0, stream>>>(gi, gh0, gh1, h_cur, enc,
                                                   e_raw, h_next, Xb, t, fast);
        k_ctx<<<dim3(4, 64), 256, 0, stream>>>(e_raw, maskf, enc, cvec, Xb, t, fast);
        if (!fast)
            k_logits<<<64, 256, 0, stream>>>(h_next, cvec, Wout, bout, out, t);
    }
    if (fast)
        k_final<<<dim3(128, 16), 256, 0, stream>>>(Xb, Wb, bout, out);
}

// Round 5
// 10363.600 us; speedup vs baseline: 1.2148x; 1.2148x over previous
//
#include <hip/hip_runtime.h>
#include <hip/hip_bf16.h>
#include <math.h>

#define B_ 64
#define T_ 256
#define C_ 2048
#define WE_ 256
#define H_ 1024
#define G3_ 3072

typedef __attribute__((ext_vector_type(8))) short short8;
typedef __attribute__((ext_vector_type(4))) float f32x4;

__device__ __forceinline__ float sigmoidf_(float x) { return 1.f / (1.f + expf(-x)); }

__device__ __forceinline__ unsigned short f2bf(float v) {
    union { float f; unsigned int u; } x; x.f = v;
    unsigned int r = x.u + 0x7fffu + ((x.u >> 16) & 1u);
    return (unsigned short)(r >> 16);
}
__device__ __forceinline__ float bf2f(unsigned short h) {
    union { unsigned int u; float f; } x; x.u = ((unsigned int)h) << 16;
    return x.f;
}

#define LD8(p, off) (*(const short8*)((p) + (off)))

// ---------------- prep ----------------

__global__ void k_maskprep(const unsigned char* __restrict__ m, float* __restrict__ mf) {
    int idx = blockIdx.x * 256 + threadIdx.x;  // 0..16383
    bool bytemode = (m[1] != 0);               // mask[0][1] always true (words_num>=128)
    unsigned char v = bytemode ? m[idx] : m[(size_t)idx * 4];
    mf[idx] = v ? 1.f : 0.f;
}

// slot 0 of H ([t][b][k] layout): h0 = enc[:, -1, :]
__global__ void k_hinit0(const float* __restrict__ enc,
                         unsigned short* __restrict__ Hh, unsigned short* __restrict__ Hl) {
    int idx = blockIdx.x * 256 + threadIdx.x;  // 0..65535 = b*1024+k
    int b = idx >> 10, k = idx & 1023;
    float v = enc[((size_t)b * T_ + (T_ - 1)) * H_ + k];
    unsigned short hi = f2bf(v);
    Hh[idx] = hi;
    Hl[idx] = f2bf(v - bf2f(hi));
}

// Wg[j][k] (3072 x 1280): k<256 -> Wih, k>=256 -> Whh; hi/lo bf16.
__global__ void k_wgprep(const float* __restrict__ Wih, const float* __restrict__ Whh,
                         unsigned short* __restrict__ Wgh, unsigned short* __restrict__ Wgl) {
    int row = blockIdx.x;          // 0..3071
    int c4 = threadIdx.x;          // 0..319
    int col = c4 * 4;
    float4 v = (col < 256) ? *(const float4*)&Wih[(size_t)row * 256 + col]
                           : *(const float4*)&Whh[(size_t)row * 1024 + col - 256];
    unsigned short h[4], l[4];
    float vv[4] = {v.x, v.y, v.z, v.w};
#pragma unroll
    for (int i = 0; i < 4; ++i) { h[i] = f2bf(vv[i]); l[i] = f2bf(vv[i] - bf2f(h[i])); }
    size_t o = (size_t)row * 1280 + col;
    *(uint2*)&Wgh[o] = *(const uint2*)h;
    *(uint2*)&Wgl[o] = *(const uint2*)l;
}

// Xe[t][b][e] hi/lo bf16
__global__ void k_xemb(const float* __restrict__ E, const int* __restrict__ targets,
                       unsigned short* __restrict__ Xeh, unsigned short* __restrict__ Xel) {
    int t = blockIdx.x, b = blockIdx.y, l = threadIdx.x;  // l 0..63
    int id = (t == 0) ? 0 : targets[b * T_ + t - 1];
    float4 v = *(const float4*)&E[(size_t)id * 256 + l * 4];
    unsigned short h[4], lo[4];
    float vv[4] = {v.x, v.y, v.z, v.w};
#pragma unroll
    for (int i = 0; i < 4; ++i) { h[i] = f2bf(vv[i]); lo[i] = f2bf(vv[i] - bf2f(h[i])); }
    size_t o = (size_t)t * 16384 + (size_t)b * 256 + l * 4;
    *(uint2*)&Xeh[o] = *(const uint2*)h;
    *(uint2*)&Xel[o] = *(const uint2*)lo;
}

__global__ void k_encprep(const float* __restrict__ enc,
                          unsigned short* __restrict__ ench, unsigned short* __restrict__ encl) {
    size_t i4 = (size_t)blockIdx.x * 256 + threadIdx.x;
    float4 v = *(const float4*)&enc[i4 * 4];
    unsigned short h[4], l[4];
    float vv[4] = {v.x, v.y, v.z, v.w};
#pragma unroll
    for (int i = 0; i < 4; ++i) { h[i] = f2bf(vv[i]); l[i] = f2bf(vv[i] - bf2f(h[i])); }
    *(uint2*)&ench[i4 * 4] = *(const uint2*)h;
    *(uint2*)&encl[i4 * 4] = *(const uint2*)l;
}

__global__ void k_wprep(const float* __restrict__ Wout, unsigned short* __restrict__ Wb) {
    int i4 = blockIdx.x * 256 + threadIdx.x;
    float4 v = *(const float4*)&Wout[(size_t)i4 * 4];
    unsigned short t[4] = {f2bf(v.x), f2bf(v.y), f2bf(v.z), f2bf(v.w)};
    *(uint2*)&Wb[(size_t)i4 * 4] = *(const uint2*)t;
}

// ---------------- one GRU step: LDS-free direct-L2 MFMA GEMM ----------------
// grid 64 (j-triples of 16), block 512 = 8 waves = 4 m-waves x 2 k-subhalves (640).
// A/B fragments loaded straight from global (L2-hot weights, L3->L2 h slot).
// One LDS bounce to reduce the K-split; GRU epilogue in ksub0 waves.
__global__ __launch_bounds__(512, 1) void k_step2(
    const unsigned short* __restrict__ Xeh, const unsigned short* __restrict__ Xel,
    const unsigned short* __restrict__ Wgh, const unsigned short* __restrict__ Wgl,
    const float* __restrict__ bih, const float* __restrict__ bhh,
    unsigned short* __restrict__ Hh, unsigned short* __restrict__ Hl,
    int t)
{
    __shared__ float red[3072];   // 4 m-waves x 3 accs x 64 lanes x f32x4
    const int tid = threadIdx.x;
    const int wave = tid >> 6, lane = tid & 63;
    const int ml = lane & 15, quad = lane >> 4;
    const int mw = wave & 3, ksub = wave >> 2;
    const int j0 = blockIdx.x * 16;
    const int m0 = mw * 16;
    const int kbase = ksub * 640;

    // B row pointers
    const size_t bo = (size_t)(j0 + ml) * 1280 + quad * 8;
    const unsigned short* BrH = Wgh + bo;
    const unsigned short* BrL = Wgl + bo;
    const unsigned short* BzH = Wgh + bo + (size_t)1024 * 1280;
    const unsigned short* BzL = Wgl + bo + (size_t)1024 * 1280;
    const unsigned short* BnH = Wgh + bo + (size_t)2048 * 1280;
    const unsigned short* BnL = Wgl + bo + (size_t)2048 * 1280;

    // A pointers
    const unsigned short* AxH = Xeh + (size_t)t * 16384 + (size_t)(m0 + ml) * 256 + quad * 8;
    const unsigned short* AxL = Xel + (size_t)t * 16384 + (size_t)(m0 + ml) * 256 + quad * 8;
    // arranged so (ptr + k0) is valid for k0 in [256,1280):
    const unsigned short* AhH = Hh + (size_t)t * 65536 + (size_t)(m0 + ml) * 1024 + quad * 8 - 256;
    const unsigned short* AhL = Hl + (size_t)t * 65536 + (size_t)(m0 + ml) * 1024 + quad * 8 - 256;

    f32x4 aR = {0,0,0,0}, aZ = {0,0,0,0}, aNX = {0,0,0,0}, aNH = {0,0,0,0};

#pragma unroll
    for (int c = 0; c < 20; ++c) {
        const int k0 = kbase + c * 32;          // wave-uniform
        short8 ah, al;
        if (k0 < 256) { ah = LD8(AxH, k0); al = LD8(AxL, k0); }
        else          { ah = LD8(AhH, k0); al = LD8(AhL, k0); }
        short8 b0h = LD8(BrH, k0), b0l = LD8(BrL, k0);
        short8 b1h = LD8(BzH, k0), b1l = LD8(BzL, k0);
        short8 b2h = LD8(BnH, k0), b2l = LD8(BnL, k0);
        aR = __builtin_amdgcn_mfma_f32_16x16x32_bf16(ah, b0h, aR, 0, 0, 0);
        aR = __builtin_amdgcn_mfma_f32_16x16x32_bf16(ah, b0l, aR, 0, 0, 0);
        aR = __builtin_amdgcn_mfma_f32_16x16x32_bf16(al, b0h, aR, 0, 0, 0);
        aZ = __builtin_amdgcn_mfma_f32_16x16x32_bf16(ah, b1h, aZ, 0, 0, 0);
        aZ = __builtin_amdgcn_mfma_f32_16x16x32_bf16(ah, b1l, aZ, 0, 0, 0);
        aZ = __builtin_amdgcn_mfma_f32_16x16x32_bf16(al, b1h, aZ, 0, 0, 0);
        if (k0 < 256) {
            aNX = __builtin_amdgcn_mfma_f32_16x16x32_bf16(ah, b2h, aNX, 0, 0, 0);
            aNX = __builtin_amdgcn_mfma_f32_16x16x32_bf16(ah, b2l, aNX, 0, 0, 0);
            aNX = __builtin_amdgcn_mfma_f32_16x16x32_bf16(al, b2h, aNX, 0, 0, 0);
        } else {
            aNH = __builtin_amdgcn_mfma_f32_16x16x32_bf16(ah, b2h, aNH, 0, 0, 0);
            aNH = __builtin_amdgcn_mfma_f32_16x16x32_bf16(ah, b2l, aNH, 0, 0, 0);
            aNH = __builtin_amdgcn_mfma_f32_16x16x32_bf16(al, b2h, aNH, 0, 0, 0);
        }
    }

    // reduce K-split via LDS
    if (ksub == 1) {
        *(f32x4*)&red[((mw * 3 + 0) * 64 + lane) * 4] = aR;
        *(f32x4*)&red[((mw * 3 + 1) * 64 + lane) * 4] = aZ;
        *(f32x4*)&red[((mw * 3 + 2) * 64 + lane) * 4] = aNH;
    }
    __syncthreads();
    if (ksub == 0) {
        aR  += *(const f32x4*)&red[((mw * 3 + 0) * 64 + lane) * 4];
        aZ  += *(const f32x4*)&red[((mw * 3 + 1) * 64 + lane) * 4];
        aNH += *(const f32x4*)&red[((mw * 3 + 2) * 64 + lane) * 4];

        const int j = j0 + ml;
        const float bRv = bih[j] + bhh[j];
        const float bZv = bih[1024 + j] + bhh[1024 + j];
        const float bNXv = bih[2048 + j];
        const float bNHv = bhh[2048 + j];
        const size_t slotT = (size_t)t * 65536;
        const size_t slotN = (size_t)(t + 1) * 65536;
#pragma unroll
        for (int reg = 0; reg < 4; ++reg) {
            int b = m0 + quad * 4 + reg;
            float rr = sigmoidf_(aR[reg] + bRv);
            float zz = sigmoidf_(aZ[reg] + bZv);
            float nn = tanhf((aNX[reg] + bNXv) + rr * (aNH[reg] + bNHv));
            size_t po = (size_t)b * 1024 + j;
            float hp = bf2f(Hh[slotT + po]) + bf2f(Hl[slotT + po]);
            float hv = (1.f - zz) * nn + zz * hp;
            unsigned short hi = f2bf(hv);
            Hh[slotN + po] = hi;
            Hl[slotN + po] = f2bf(hv - bf2f(hi));
        }
    }
}

// ---------------- batched attention + logits ----------------

// e[b][t][t'] = h_t[b] . enc[b][t'], bf16x2 MFMA. grid (4, 64).
__global__ __launch_bounds__(256) void k_scoresK(
    const unsigned short* __restrict__ Hh, const unsigned short* __restrict__ Hl,
    const unsigned short* __restrict__ ench, const unsigned short* __restrict__ encl,
    float* __restrict__ e_all)
{
    __shared__ unsigned short Ahs[128 * 40], Als[128 * 40], Bhs[128 * 40], Bls[128 * 40];
    const int tid = threadIdx.x;
    const int b = blockIdx.y;
    const int t0 = (blockIdx.x & 1) * 128, p0 = (blockIdx.x >> 1) * 128;
    const int lane = tid & 63, wave = tid >> 6;
    const int wm = (wave & 1) * 64, wn = (wave >> 1) * 64;
    const int ml = lane & 15, quad = lane >> 4;
    f32x4 acc[4][4];
#pragma unroll
    for (int a = 0; a < 4; ++a)
#pragma unroll
        for (int c = 0; c < 4; ++c) acc[a][c] = (f32x4){0.f, 0.f, 0.f, 0.f};

    for (int kc = 0; kc < 32; ++kc) {
#pragma unroll
        for (int r2 = 0; r2 < 2; ++r2) {
            int s = tid + 256 * r2;
            int row = s >> 2, q = s & 3;
            size_t ga = ((size_t)(t0 + row + 1) * 64 + b) * 1024 + kc * 32 + q * 8;
            size_t gb = ((size_t)b * 256 + p0 + row) * 1024 + kc * 32 + q * 8;
            *(uint4*)&Ahs[row * 40 + q * 8] = *(const uint4*)&Hh[ga];
            *(uint4*)&Als[row * 40 + q * 8] = *(const uint4*)&Hl[ga];
            *(uint4*)&Bhs[row * 40 + q * 8] = *(const uint4*)&ench[gb];
            *(uint4*)&Bls[row * 40 + q * 8] = *(const uint4*)&encl[gb];
        }
        __syncthreads();
        short8 ah[4], al[4], bh[4], bl[4];
#pragma unroll
        for (int mt = 0; mt < 4; ++mt) {
            ah[mt] = *(const short8*)&Ahs[(wm + mt * 16 + ml) * 40 + quad * 8];
            al[mt] = *(const short8*)&Als[(wm + mt * 16 + ml) * 40 + quad * 8];
        }
#pragma unroll
        for (int nt = 0; nt < 4; ++nt) {
            bh[nt] = *(const short8*)&Bhs[(wn + nt * 16 + ml) * 40 + quad * 8];
            bl[nt] = *(const short8*)&Bls[(wn + nt * 16 + ml) * 40 + quad * 8];
        }
#pragma unroll
        for (int mt = 0; mt < 4; ++mt)
#pragma unroll
            for (int nt = 0; nt < 4; ++nt) {
                acc[mt][nt] = __builtin_amdgcn_mfma_f32_16x16x32_bf16(ah[mt], bh[nt], acc[mt][nt], 0, 0, 0);
                acc[mt][nt] = __builtin_amdgcn_mfma_f32_16x16x32_bf16(ah[mt], bl[nt], acc[mt][nt], 0, 0, 0);
                acc[mt][nt] = __builtin_amdgcn_mfma_f32_16x16x32_bf16(al[mt], bh[nt], acc[mt][nt], 0, 0, 0);
            }
        __syncthreads();
    }
#pragma unroll
    for (int mt = 0; mt < 4; ++mt)
#pragma unroll
        for (int nt = 0; nt < 4; ++nt)
#pragma unroll
            for (int reg = 0; reg < 4; ++reg) {
                int t = t0 + wm + mt * 16 + quad * 4 + reg;
                int p = p0 + wn + nt * 16 + ml;
                e_all[((size_t)b * 256 + t) * 256 + p] = acc[mt][nt][reg];
            }
}

__global__ __launch_bounds__(256) void k_softmaxK(
    const float* __restrict__ e_all, const float* __restrict__ maskf,
    unsigned short* __restrict__ Ab)
{
    const int tid = threadIdx.x;
    const int ridx = blockIdx.x * 4 + (tid >> 6);
    const int lane = tid & 63;
    const int b = ridx >> 8, t = ridx & 255;
    const float* er = e_all + ((size_t)b * 256 + t) * 256;
    const float* mr = maskf + (size_t)b * 256;
    float v[4];
#pragma unroll
    for (int i = 0; i < 4; ++i) {
        int p = lane + 64 * i;
        v[i] = (mr[p] > 0.5f) ? er[p] : -INFINITY;
    }
    float m = fmaxf(fmaxf(v[0], v[1]), fmaxf(v[2], v[3]));
#pragma unroll
    for (int off = 32; off > 0; off >>= 1) m = fmaxf(m, __shfl_xor(m, off));
    float s = 0.f;
#pragma unroll
    for (int i = 0; i < 4; ++i) { v[i] = expf(v[i] - m); s += v[i]; }
#pragma unroll
    for (int off = 32; off > 0; off >>= 1) s += __shfl_xor(s, off);
    float inv = 1.f / s;
    unsigned short* arr = Ab + ((size_t)b * 256 + t) * 256;
#pragma unroll
    for (int i = 0; i < 4; ++i) arr[lane + 64 * i] = f2bf(v[i] * inv);
}

// C[b][t][k] = sum_t' alpha[b][t][t'] * enc[b][t'][k]. grid (16, 64).
__global__ __launch_bounds__(256) void k_contextK(
    const unsigned short* __restrict__ Ab, const unsigned short* __restrict__ ench,
    unsigned short* __restrict__ Cb)
{
    __shared__ unsigned short As[128 * 40];
    __shared__ unsigned short Bs[128 * 40];   // [k][t'] transposed
    const int tid = threadIdx.x;
    const int b = blockIdx.y;
    const int t0 = (blockIdx.x & 1) * 128;
    const int k0 = (blockIdx.x >> 1) * 128;
    const int lane = tid & 63, wave = tid >> 6;
    const int wm = (wave & 1) * 64, wn = (wave >> 1) * 64;
    const int ml = lane & 15, quad = lane >> 4;
    f32x4 acc[4][4];
#pragma unroll
    for (int a = 0; a < 4; ++a)
#pragma unroll
        for (int c = 0; c < 4; ++c) acc[a][c] = (f32x4){0.f, 0.f, 0.f, 0.f};

    for (int c = 0; c < 8; ++c) {
#pragma unroll
        for (int r2 = 0; r2 < 2; ++r2) {
            int s = tid + 256 * r2;
            int row = s >> 2, q = s & 3;
            *(uint4*)&As[row * 40 + q * 8] =
                *(const uint4*)&Ab[((size_t)b * 256 + t0 + row) * 256 + c * 32 + q * 8];
        }
        {
            int tr = tid >> 3, kq = tid & 7;
            const unsigned short* src =
                ench + ((size_t)b * 256 + c * 32 + tr) * 1024 + k0 + kq * 16;
            unsigned short tmp[16];
            *(uint4*)&tmp[0] = *(const uint4*)&src[0];
            *(uint4*)&tmp[8] = *(const uint4*)&src[8];
#pragma unroll
            for (int i = 0; i < 16; ++i)
                Bs[(kq * 16 + i) * 40 + tr] = tmp[i];
        }
        __syncthreads();
        short8 af[4], bf[4];
#pragma unroll
        for (int mt = 0; mt < 4; ++mt)
            af[mt] = *(const short8*)&As[(wm + mt * 16 + ml) * 40 + quad * 8];
#pragma unroll
        for (int nt = 0; nt < 4; ++nt)
            bf[nt] = *(const short8*)&Bs[(wn + nt * 16 + ml) * 40 + quad * 8];
#pragma unroll
        for (int mt = 0; mt < 4; ++mt)
#pragma unroll
            for (int nt = 0; nt < 4; ++nt)
                acc[mt][nt] = __builtin_amdgcn_mfma_f32_16x16x32_bf16(af[mt], bf[nt], acc[mt][nt], 0, 0, 0);
        __syncthreads();
    }
#pragma unroll
    for (int mt = 0; mt < 4; ++mt)
#pragma unroll
        for (int nt = 0; nt < 4; ++nt)
#pragma unroll
            for (int reg = 0; reg < 4; ++reg) {
                int t = t0 + wm + mt * 16 + quad * 4 + reg;
                int k = k0 + wn + nt * 16 + ml;
                Cb[((size_t)b * 256 + t) * 1024 + k] = f2bf(acc[mt][nt][reg]);
            }
}

// out[r][j] = [H|C][r] . Wb[j] + bout[j]; M=16384, N=2048, K=2048. r = b*256+t.
__global__ __launch_bounds__(256) void k_finalK(
    const unsigned short* __restrict__ Hh, const unsigned short* __restrict__ Cb,
    const unsigned short* __restrict__ Wb,
    const float* __restrict__ bout, float* __restrict__ out)
{
    __shared__ unsigned short As[128 * 40];
    __shared__ unsigned short Bs[128 * 40];
    const int tid = threadIdx.x;
    const int gr0 = blockIdx.x * 128;
    const int j0  = blockIdx.y * 128;
    const int lane = tid & 63, wave = tid >> 6;
    const int wm = (wave & 1) * 64, wn = (wave >> 1) * 64;
    const int ml = lane & 15, quad = lane >> 4;
    f32x4 acc[4][4];
#pragma unroll
    for (int a = 0; a < 4; ++a)
#pragma unroll
        for (int c = 0; c < 4; ++c) acc[a][c] = (f32x4){0.f, 0.f, 0.f, 0.f};

    for (int kc = 0; kc < 64; ++kc) {
        int ko = (kc & 31) * 32;
#pragma unroll
        for (int r2 = 0; r2 < 2; ++r2) {
            int s = tid + 256 * r2;
            int row = s >> 2, q = s & 3;
            int r0 = gr0 + row;
            size_t ga;
            if (kc < 32) ga = ((size_t)((r0 & 255) + 1) * 64 + (r0 >> 8)) * 1024 + ko + q * 8;
            else         ga = (size_t)r0 * 1024 + ko + q * 8;
            const unsigned short* asrc = (kc < 32) ? Hh : Cb;
            *(uint4*)&As[row * 40 + q * 8] = *(const uint4*)&asrc[ga];
            *(uint4*)&Bs[row * 40 + q * 8] =
                *(const uint4*)&Wb[(size_t)(j0 + row) * 2048 + kc * 32 + q * 8];
        }
        __syncthreads();
        short8 af[4], bf[4];
#pragma unroll
        for (int mt = 0; mt < 4; ++mt)
            af[mt] = *(const short8*)&As[(wm + mt * 16 + ml) * 40 + quad * 8];
#pragma unroll
        for (int nt = 0; nt < 4; ++nt)
            bf[nt] = *(const short8*)&Bs[(wn + nt * 16 + ml) * 40 + quad * 8];
#pragma unroll
        for (int mt = 0; mt < 4; ++mt)
#pragma unroll
            for (int nt = 0; nt < 4; ++nt)
                acc[mt][nt] = __builtin_amdgcn_mfma_f32_16x16x32_bf16(af[mt], bf[nt], acc[mt][nt], 0, 0, 0);
        __syncthreads();
    }
#pragma unroll
    for (int nt = 0; nt < 4; ++nt) {
        int j = j0 + wn + nt * 16 + ml;
        float bo = bout[j];
#pragma unroll
        for (int mt = 0; mt < 4; ++mt)
#pragma unroll
            for (int reg = 0; reg < 4; ++reg) {
                int r = gr0 + wm + mt * 16 + quad * 4 + reg;
                out[(size_t)r * 2048 + j] = acc[mt][nt][reg] + bo;
            }
    }
}

// ---------------- FALLBACK (round-2) path ----------------

__global__ void k_hinit(const float* __restrict__ enc, float* __restrict__ h) {
    int idx = blockIdx.x * 256 + threadIdx.x;
    int b = idx >> 10, k = idx & (H_ - 1);
    h[idx] = enc[((size_t)b * T_ + (T_ - 1)) * H_ + k];
}

__global__ __launch_bounds__(256) void k_gates(
    const float* __restrict__ E, const int* __restrict__ targets,
    const float* __restrict__ Wih, const float* __restrict__ Whh,
    const float* __restrict__ bih, const float* __restrict__ bhh,
    const float* __restrict__ h_cur,
    float* __restrict__ gi, float* __restrict__ gh0, float* __restrict__ gh1,
    int t)
{
    __shared__ float As[32 * 68];
    __shared__ float Ws[32 * 34];
    __shared__ int ids[B_];
    const int tid = threadIdx.x;
    const int z = blockIdx.y;
    const int j0 = blockIdx.x * 32;
    const int tx = tid & 15;
    const int ty = tid >> 4;
    float accI[4][2], accH[4][2];
#pragma unroll
    for (int i = 0; i < 4; ++i) { accI[i][0]=0.f; accI[i][1]=0.f; accH[i][0]=0.f; accH[i][1]=0.f; }
    if (tid < B_) ids[tid] = (t == 0) ? 0 : targets[tid * T_ + t - 1];
    __syncthreads();
    if (z == 0) {
        for (int c = 0; c < 8; ++c) {
            int k0 = c * 32;
#pragma unroll
            for (int r = 0; r < 2; ++r) {
                int lin = tid + 256 * r;
                int k4 = lin & 7, b = lin >> 3;
                float4 v = *(const float4*)&E[(size_t)ids[b] * WE_ + k0 + k4 * 4];
                int kk = k4 * 4;
                As[(kk + 0) * 68 + b] = v.x; As[(kk + 1) * 68 + b] = v.y;
                As[(kk + 2) * 68 + b] = v.z; As[(kk + 3) * 68 + b] = v.w;
            }
            {
                int k4 = tid & 7, jj = tid >> 3;
                float4 v = *(const float4*)&Wih[(size_t)(j0 + jj) * WE_ + k0 + k4 * 4];
                int kk = k4 * 4;
                Ws[(kk + 0) * 34 + jj] = v.x; Ws[(kk + 1) * 34 + jj] = v.y;
                Ws[(kk + 2) * 34 + jj] = v.z; Ws[(kk + 3) * 34 + jj] = v.w;
            }
            __syncthreads();
#pragma unroll
            for (int kk = 0; kk < 32; ++kk) {
                float4 a = *(const float4*)&As[kk * 68 + ty * 4];
                float2 w = *(const float2*)&Ws[kk * 34 + tx * 2];
                accI[0][0] += a.x * w.x; accI[0][1] += a.x * w.y;
                accI[1][0] += a.y * w.x; accI[1][1] += a.y * w.y;
                accI[2][0] += a.z * w.x; accI[2][1] += a.z * w.y;
                accI[3][0] += a.w * w.x; accI[3][1] += a.w * w.y;
            }
            __syncthreads();
        }
    }
    const int c_lo = (z == 0) ? 0 : 12;
    const int c_hi = (z == 0) ? 12 : 32;
    for (int c = c_lo; c < c_hi; ++c) {
        int k0 = c * 32;
#pragma unroll
        for (int r = 0; r < 2; ++r) {
            int lin = tid + 256 * r;
            int k4 = lin & 7, b = lin >> 3;
            float4 v = *(const float4*)&h_cur[(size_t)b * H_ + k0 + k4 * 4];
            int kk = k4 * 4;
            As[(kk + 0) * 68 + b] = v.x; As[(kk + 1) * 68 + b] = v.y;
            As[(kk + 2) * 68 + b] = v.z; As[(kk + 3) * 68 + b] = v.w;
        }
        {
            int k4 = tid & 7, jj = tid >> 3;
            float4 v = *(const float4*)&Whh[(size_t)(j0 + jj) * H_ + k0 + k4 * 4];
            int kk = k4 * 4;
            Ws[(kk + 0) * 34 + jj] = v.x; Ws[(kk + 1) * 34 + jj] = v.y;
            Ws[(kk + 2) * 34 + jj] = v.z; Ws[(kk + 3) * 34 + jj] = v.w;
        }
        __syncthreads();
#pragma unroll
        for (int kk = 0; kk < 32; ++kk) {
            float4 a = *(const float4*)&As[kk * 68 + ty * 4];
            float2 w = *(const float2*)&Ws[kk * 34 + tx * 2];
            accH[0][0] += a.x * w.x; accH[0][1] += a.x * w.y;
            accH[1][0] += a.y * w.x; accH[1][1] += a.y * w.y;
            accH[2][0] += a.z * w.x; accH[2][1] += a.z * w.y;
            accH[3][0] += a.w * w.x; accH[3][1] += a.w * w.y;
        }
        __syncthreads();
    }
#pragma unroll
    for (int p = 0; p < 2; ++p) {
        int j = j0 + tx * 2 + p;
        if (z == 0) {
            float vi = bih[j], vh = bhh[j];
#pragma unroll
            for (int i = 0; i < 4; ++i) {
                int b = ty * 4 + i;
                gi[(size_t)b * G3_ + j]  = accI[i][p] + vi;
                gh0[(size_t)b * G3_ + j] = accH[i][p] + vh;
            }
        } else {
#pragma unroll
            for (int i = 0; i < 4; ++i) {
                int b = ty * 4 + i;
                gh1[(size_t)b * G3_ + j] = accH[i][p];
            }
        }
    }
}

__global__ __launch_bounds__(256) void k_score_h(
    const float* __restrict__ gi, const float* __restrict__ gh0, const float* __restrict__ gh1,
    const float* __restrict__ h_prev, const float* __restrict__ enc,
    float* __restrict__ e_raw, float* __restrict__ h_next,
    __hip_bfloat16* __restrict__ Xb, int t, int use_x)
{
    __shared__ float hs[H_];
    const int b = blockIdx.y;
    const int tc = blockIdx.x;
    const int tid = threadIdx.x;
#pragma unroll
    for (int i = 0; i < 4; ++i) {
        int k = i * 256 + tid;
        size_t o = (size_t)b * G3_ + k;
        float ir = gi[o], iz = gi[o + H_], in = gi[o + 2 * H_];
        float hr = gh0[o] + gh1[o];
        float hz = gh0[o + H_] + gh1[o + H_];
        float hn = gh0[o + 2 * H_] + gh1[o + 2 * H_];
        float r = sigmoidf_(ir + hr);
        float z = sigmoidf_(iz + hz);
        float n = tanhf(in + r * hn);
        float hv = (1.f - z) * n + z * h_prev[(size_t)b * H_ + k];
        hs[k] = hv;
        if (tc == 0) {
            h_next[(size_t)b * H_ + k] = hv;
            if (use_x) Xb[((size_t)b * T_ + t) * C_ + k] = __float2bfloat16(hv);
        }
    }
    __syncthreads();
    const int tl = tid >> 2, part = tid & 3;
    const int tt = tc * 64 + tl;
    const float4* row = (const float4*)(enc + ((size_t)b * T_ + tt) * H_);
    const float4* hv4 = (const float4*)hs;
    float acc = 0.f;
#pragma unroll 8
    for (int i = 0; i < 64; ++i) {
        float4 a = row[part * 64 + i];
        float4 x = hv4[part * 64 + i];
        acc += a.x * x.x + a.y * x.y + a.z * x.z + a.w * x.w;
    }
    acc += __shfl_xor(acc, 1);
    acc += __shfl_xor(acc, 2);
    if (part == 0) e_raw[(size_t)b * T_ + tt] = acc;
}

__global__ __launch_bounds__(256) void k_ctx(
    const float* __restrict__ e_raw, const float* __restrict__ maskf,
    const float* __restrict__ enc, float* __restrict__ cvec,
    __hip_bfloat16* __restrict__ Xb, int t, int use_x)
{
    __shared__ float al[T_];
    __shared__ float red[256];
    const int b = blockIdx.y, q = blockIdx.x, tid = threadIdx.x;
    float e = (maskf[(size_t)b * T_ + tid] > 0.5f) ? e_raw[(size_t)b * T_ + tid] : -INFINITY;
    red[tid] = e; __syncthreads();
    for (int s = 128; s > 0; s >>= 1) { if (tid < s) red[tid] = fmaxf(red[tid], red[tid + s]); __syncthreads(); }
    float mx = red[0]; __syncthreads();
    float p = expf(e - mx);
    red[tid] = p; __syncthreads();
    for (int s = 128; s > 0; s >>= 1) { if (tid < s) red[tid] += red[tid + s]; __syncthreads(); }
    float denom = red[0];
    al[tid] = p / denom;
    __syncthreads();
    const int k = q * 256 + tid;
    float acc = 0.f;
#pragma unroll 8
    for (int tt2 = 0; tt2 < T_; ++tt2) {
        acc += al[tt2] * enc[((size_t)b * T_ + tt2) * H_ + k];
    }
    if (use_x) Xb[((size_t)b * T_ + t) * C_ + H_ + k] = __float2bfloat16(acc);
    else       cvec[(size_t)b * H_ + k] = acc;
}

__global__ __launch_bounds__(256) void k_logits(
    const float* __restrict__ h, const float* __restrict__ cvec,
    const float* __restrict__ Wout, const float* __restrict__ bout,
    float* __restrict__ out, int t)
{
    __shared__ float As[32 * 68];
    __shared__ float Ws[32 * 33];
    const int tid = threadIdx.x;
    const int j0 = blockIdx.x * 32;
    const int tx = tid & 31;
    const int ty = tid >> 5;
    float acc[8];
#pragma unroll
    for (int i = 0; i < 8; ++i) acc[i] = 0.f;
    for (int c = 0; c < 64; ++c) {
        int k0 = c * 32;
        const float* Ap = (k0 < H_) ? (h + k0) : (cvec + (k0 - H_));
#pragma unroll
        for (int r = 0; r < 2; ++r) {
            int lin = tid + 256 * r;
            int k4 = lin & 7, b = lin >> 3;
            float4 v = *(const float4*)&Ap[(size_t)b * H_ + k4 * 4];
            int kk = k4 * 4;
            As[(kk + 0) * 68 + b] = v.x; As[(kk + 1) * 68 + b] = v.y;
            As[(kk + 2) * 68 + b] = v.z; As[(kk + 3) * 68 + b] = v.w;
        }
        {
            int k4 = tid & 7, jj = tid >> 3;
            float4 v = *(const float4*)&Wout[(size_t)(j0 + jj) * (2 * H_) + k0 + k4 * 4];
            int kk = k4 * 4;
            Ws[(kk + 0) * 33 + jj] = v.x; Ws[(kk + 1) * 33 + jj] = v.y;
            Ws[(kk + 2) * 33 + jj] = v.z; Ws[(kk + 3) * 33 + jj] = v.w;
        }
        __syncthreads();
#pragma unroll
        for (int kk = 0; kk < 32; ++kk) {
            float w = Ws[kk * 33 + tx];
#pragma unroll
            for (int i = 0; i < 8; ++i) acc[i] += As[kk * 68 + ty * 8 + i] * w;
        }
        __syncthreads();
    }
    float bo = bout[j0 + tx];
#pragma unroll
    for (int i = 0; i < 8; ++i) {
        int b = ty * 8 + i;
        out[((size_t)b * T_ + t) * C_ + j0 + tx] = acc[i] + bo;
    }
}

__global__ __launch_bounds__(256) void k_final(
    const __hip_bfloat16* __restrict__ Xb, const __hip_bfloat16* __restrict__ Wb,
    const float* __restrict__ bout, float* __restrict__ out)
{
    __shared__ __hip_bfloat16 As[128 * 40];
    __shared__ __hip_bfloat16 Bs[128 * 40];
    const int tid = threadIdx.x;
    const int gr0 = blockIdx.x * 128;
    const int j0  = blockIdx.y * 128;
    const int lane = tid & 63, wave = tid >> 6;
    const int wm = (wave & 1) * 64, wn = (wave >> 1) * 64;
    const int ml = lane & 15, quad = lane >> 4;
    f32x4 acc[4][4];
#pragma unroll
    for (int a = 0; a < 4; ++a)
#pragma unroll
        for (int b = 0; b < 4; ++b) acc[a][b] = (f32x4){0.f, 0.f, 0.f, 0.f};
    for (int kc = 0; kc < 64; ++kc) {
#pragma unroll
        for (int r = 0; r < 2; ++r) {
            int s = tid + 256 * r;
            int row = s >> 2, kq = s & 3;
            *(uint4*)&As[row * 40 + kq * 8] =
                *(const uint4*)&Xb[(size_t)(gr0 + row) * 2048 + kc * 32 + kq * 8];
            *(uint4*)&Bs[row * 40 + kq * 8] =
                *(const uint4*)&Wb[(size_t)(j0 + row) * 2048 + kc * 32 + kq * 8];
        }
        __syncthreads();
        short8 af[4], bf[4];
#pragma unroll
        for (int mt = 0; mt < 4; ++mt)
            af[mt] = *(const short8*)&As[(wm + mt * 16 + ml) * 40 + quad * 8];
#pragma unroll
        for (int nt = 0; nt < 4; ++nt)
            bf[nt] = *(const short8*)&Bs[(wn + nt * 16 + ml) * 40 + quad * 8];
#pragma unroll
        for (int mt = 0; mt < 4; ++mt)
#pragma unroll
            for (int nt = 0; nt < 4; ++nt)
                acc[mt][nt] = __builtin_amdgcn_mfma_f32_16x16x32_bf16(af[mt], bf[nt], acc[mt][nt], 0, 0, 0);
        __syncthreads();
    }
#pragma unroll
    for (int nt = 0; nt < 4; ++nt) {
        int j = j0 + wn + nt * 16 + ml;
        float bo = bout[j];
#pragma unroll
        for (int mt = 0; mt < 4; ++mt) {
#pragma unroll
            for (int reg = 0; reg < 4; ++reg) {
                int r = gr0 + wm + mt * 16 + quad * 4 + reg;
                out[(size_t)r * 2048 + j] = acc[mt][nt][reg] + bo;
            }
        }
    }
}

// ---------------- host ----------------

extern "C" void kernel_launch(void* const* d_in, const int* in_sizes, int n_in,
                              void* d_out, int out_size, void* d_ws, size_t ws_size,
                              hipStream_t stream)
{
    const float* enc     = (const float*)d_in[0];
    const unsigned char* mask = (const unsigned char*)d_in[1];
    const int*   targets = (const int*)d_in[2];
    const float* E       = (const float*)d_in[3];
    const float* Wih     = (const float*)d_in[4];
    const float* Whh     = (const float*)d_in[5];
    const float* bih     = (const float*)d_in[6];
    const float* bhh     = (const float*)d_in[7];
    const float* Wout    = (const float*)d_in[8];
    const float* bout    = (const float*)d_in[9];
    float* out = (float*)d_out;

    const size_t NEED_FULL = 218300416ull;  // layout below (known to fit)
    const size_t NEED_MID  = 819200ull * 4 + (4194304ull + 33554432ull) * 2;  // ~78.8 MB

    if (ws_size >= NEED_FULL) {
        char* p = (char*)d_ws;
        p += 131072;                              // (reserved, unused)
        float* maskf = (float*)p;                p += 65536;
        unsigned short* Wgh = (unsigned short*)p; p += 7864320;
        unsigned short* Wgl = (unsigned short*)p; p += 7864320;
        unsigned short* Xeh = (unsigned short*)p; p += 8388608;
        unsigned short* Xel = (unsigned short*)p; p += 8388608;
        float* e_all = (float*)Xeh;               // alias: Xe dead after recurrence
        unsigned short* ench = (unsigned short*)p; p += 33554432;
        unsigned short* encl = (unsigned short*)p; p += 33554432;
        unsigned short* Hh = (unsigned short*)p;  p += 33685504;   // 257 slots [t][b][k]
        unsigned short* Hl = (unsigned short*)p;  p += 33685504;
        unsigned short* Ab = (unsigned short*)p;  p += 8388608;
        unsigned short* Cb = (unsigned short*)p;  p += 33554432;
        unsigned short* Wb = (unsigned short*)p;  p += 8388608;

        k_maskprep<<<64, 256, 0, stream>>>(mask, maskf);
        k_hinit0<<<256, 256, 0, stream>>>(enc, Hh, Hl);
        k_wgprep<<<3072, 320, 0, stream>>>(Wih, Whh, Wgh, Wgl);
        k_xemb<<<dim3(256, 64), 64, 0, stream>>>(E, targets, Xeh, Xel);
        k_encprep<<<16384, 256, 0, stream>>>(enc, ench, encl);
        k_wprep<<<4096, 256, 0, stream>>>(Wout, Wb);

        for (int t = 0; t < T_; ++t)
            k_step2<<<64, 512, 0, stream>>>(Xeh, Xel, Wgh, Wgl, bih, bhh, Hh, Hl, t);

        k_scoresK<<<dim3(4, 64), 256, 0, stream>>>(Hh, Hl, ench, encl, e_all);
        k_softmaxK<<<4096, 256, 0, stream>>>(e_all, maskf, Ab);
        k_contextK<<<dim3(16, 64), 256, 0, stream>>>(Ab, ench, Cb);
        k_finalK<<<dim3(128, 16), 256, 0, stream>>>(Hh, Cb, Wb, bout, out);
        return;
    }

    // ---- fallback: round-2 structure ----
    float* ws    = (float*)d_ws;
    float* hbuf  = ws;
    float* gi    = ws + 131072;
    float* gh0   = gi + 196608;
    float* gh1   = gh0 + 196608;
    float* e_raw = gh1 + 196608;
    float* maskf = e_raw + 16384;
    float* cvec  = maskf + 16384;
    __hip_bfloat16* Wb = (__hip_bfloat16*)(ws + 819200);
    __hip_bfloat16* Xb = Wb + 4194304;

    const int fast = (ws_size >= NEED_MID) ? 1 : 0;

    k_maskprep<<<64, 256, 0, stream>>>(mask, maskf);
    k_hinit<<<256, 256, 0, stream>>>(enc, hbuf);
    if (fast) k_wprep<<<4096, 256, 0, stream>>>(Wout, (unsigned short*)Wb);

    for (int t = 0; t < T_; ++t) {
        float* h_cur  = hbuf + (t & 1) * 65536;
        float* h_next = hbuf + ((t + 1) & 1) * 65536;
        k_gates<<<dim3(96, 2), 256, 0, stream>>>(E, targets, Wih, Whh, bih, bhh,
                                                 h_cur, gi, gh0, gh1, t);
        k_score_h<<<dim3(4, 64), 256, 0, stream>>>(gi, gh0, gh1, h_cur, enc,
                                                   e_raw, h_next, Xb, t, fast);
        k_ctx<<<dim3(4, 64), 256, 0, stream>>>(e_raw, maskf, enc, cvec, Xb, t, fast);
        if (!fast)
            k_logits<<<64, 256, 0, stream>>>(h_next, cvec, Wout, bout, out, t);
    }
    if (fast)
        k_final<<<dim3(128, 16), 256, 0, stream>>>(Xb, Wb, bout, out);
}